// Round 6
// baseline (1178.555 us; speedup 1.0000x reference)
//
#include <hip/hip_runtime.h>
#include <cstddef>
#include <cstdint>

typedef unsigned short ushort_t;
typedef unsigned long long ull_t;
typedef __attribute__((ext_vector_type(8))) short short8;
typedef __attribute__((ext_vector_type(4))) float f32x4;

constexpr int D_ = 512, K_ = 8192, N_ = 16384;
constexpr float MARGIN = 0.75f;   // >= 2x max bf16 score error over 8192 cols (~0.74 bound)

// RNE float->bf16 (data has no NaN)
__device__ __forceinline__ ushort_t f2bf(float f) {
  unsigned u = __float_as_uint(f);
  return (ushort_t)((u + 0x7FFFu + ((u >> 16) & 1u)) >> 16);
}

__device__ __forceinline__ void gld16(void* l, const void* g) {
  __builtin_amdgcn_global_load_lds((const __attribute__((address_space(1))) void*)g,
                                   (__attribute__((address_space(3))) void*)l, 16, 0, 0);
}

// -------- zero worklist counter + rowbest (runs AFTER dist_mfma; aliases xb) --------
__global__ __launch_bounds__(256) void init_ws(int* counters, ull_t* rowbest) {
  int t = blockIdx.x * 256 + threadIdx.x;   // grid 64*256 == N_
  rowbest[t] = 0ull;
  if (t == 0) counters[0] = 0;
}

// -------- convert x -> bf16 --------
__global__ __launch_bounds__(256) void conv_x(const float* __restrict__ x, ushort_t* __restrict__ xb) {
  int t = blockIdx.x * 256 + threadIdx.x;
  const float4* p = (const float4*)x;
  float4 a = p[t * 2], b = p[t * 2 + 1];
  short8 v;
  v[0] = (short)f2bf(a.x); v[1] = (short)f2bf(a.y); v[2] = (short)f2bf(a.z); v[3] = (short)f2bf(a.w);
  v[4] = (short)f2bf(b.x); v[5] = (short)f2bf(b.y); v[6] = (short)f2bf(b.z); v[7] = (short)f2bf(b.w);
  *(short8*)(xb + (size_t)t * 8) = v;
}

// -------- convert embed -> bf16, ehs = 0.5*||e||^2 (fp32) --------
__global__ __launch_bounds__(256) void conv_e(const float* __restrict__ e, ushort_t* __restrict__ eb,
                                              float* __restrict__ ehs) {
  int w = (blockIdx.x * 256 + threadIdx.x) >> 6;
  int l = threadIdx.x & 63;
  const float4* p = (const float4*)(e + (size_t)w * D_);
  float4 a = p[l * 2], b = p[l * 2 + 1];
  float s = a.x * a.x + a.y * a.y + a.z * a.z + a.w * a.w
          + b.x * b.x + b.y * b.y + b.z * b.z + b.w * b.w;
  short8 v;
  v[0] = (short)f2bf(a.x); v[1] = (short)f2bf(a.y); v[2] = (short)f2bf(a.z); v[3] = (short)f2bf(a.w);
  v[4] = (short)f2bf(b.x); v[5] = (short)f2bf(b.y); v[6] = (short)f2bf(b.z); v[7] = (short)f2bf(b.w);
  *(short8*)(eb + (size_t)w * D_ + l * 8) = v;
#pragma unroll
  for (int off = 32; off; off >>= 1) s += __shfl_xor(s, off);
  if (l == 0) ehs[w] = 0.5f * s;
}

// -------- MFMA scoring: per (row, 128-col block) MAX score only --------
// grid (N_/128, K_/128), 256 threads (2x2 waves, 64x64 per wave)
__global__ __launch_bounds__(256, 3) void dist_mfma(const ushort_t* __restrict__ xb,
                                                    const ushort_t* __restrict__ eb,
                                                    const float* __restrict__ ehs,
                                                    float* __restrict__ pp) {
  __shared__ alignas(16) char lds[16384];
  char* As = lds;            // [kq(4)][row(128)] 16B chunks
  char* Bs = lds + 8192;
  const int tid = threadIdx.x, w = tid >> 6, l = tid & 63;
  const int row0 = blockIdx.x * 128, col0 = blockIdx.y * 128;
  const int wr = w >> 1, wc = w & 1;

  f32x4 acc[4][4] = {};
  for (int d0 = 0; d0 < D_; d0 += 32) {
#pragma unroll
    for (int i = 0; i < 2; ++i) {
      gld16(As + w * 2048 + i * 1024, xb + (size_t)(row0 + i * 64 + l) * D_ + d0 + w * 8);
      gld16(Bs + w * 2048 + i * 1024, eb + (size_t)(col0 + i * 64 + l) * D_ + d0 + w * 8);
    }
    __syncthreads();
    short8 a[4], b[4];
#pragma unroll
    for (int i = 0; i < 4; ++i)
      a[i] = *(const short8*)(As + (l >> 4) * 2048 + (wr * 64 + i * 16 + (l & 15)) * 16);
#pragma unroll
    for (int j = 0; j < 4; ++j)
      b[j] = *(const short8*)(Bs + (l >> 4) * 2048 + (wc * 64 + j * 16 + (l & 15)) * 16);
#pragma unroll
    for (int i = 0; i < 4; ++i)
#pragma unroll
      for (int j = 0; j < 4; ++j)
        acc[i][j] = __builtin_amdgcn_mfma_f32_16x16x32_bf16(a[i], b[j], acc[i][j], 0, 0, 0);
    __syncthreads();
  }

  // ---- light epilogue: per-row max over this wave's 64 cols, merged across lanes ----
  float eh[4];
#pragma unroll
  for (int j = 0; j < 4; ++j) eh[j] = ehs[col0 + wc * 64 + j * 16 + (l & 15)];

  const int c = l & 15, g = l >> 4;
  float myv = -3e38f;
#pragma unroll
  for (int i = 0; i < 4; ++i) {
    float mv[4];
#pragma unroll
    for (int r = 0; r < 4; ++r)
      mv[r] = fmaxf(fmaxf(acc[i][0][r] - eh[0], acc[i][1][r] - eh[1]),
                    fmaxf(acc[i][2][r] - eh[2], acc[i][3][r] - eh[3]));
#pragma unroll
    for (int m = 1; m < 16; m <<= 1)
#pragma unroll
      for (int r = 0; r < 4; ++r) mv[r] = fmaxf(mv[r], __shfl_xor(mv[r], m));
    if ((c >> 2) == i) {
      int rsel = c & 3;
      myv = (rsel == 0) ? mv[0] : (rsel == 1) ? mv[1] : (rsel == 2) ? mv[2] : mv[3];
    }
  }
  const int rib = wr * 64 + (c >> 2) * 16 + g * 4 + (c & 3);   // lane's owned row in [0,128)

  // cross-wave (wc) max via LDS (staging LDS is dead after final __syncthreads)
  float* lm = (float*)lds;           // [2][128]
  lm[wc * 128 + rib] = myv;
  __syncthreads();
  if (wc == 0)
    pp[(size_t)(row0 + rib) * 64 + blockIdx.y] = fmaxf(myv, lm[128 + rib]);
}

// -------- combine block maxes; flag every block within MARGIN of the row max --------
__global__ __launch_bounds__(256) void combine(const float* __restrict__ pp,
                                               int* __restrict__ wl, int* __restrict__ counters) {
  int row = (blockIdx.x * 256 + threadIdx.x) >> 6;
  int l = threadIdx.x & 63;
  float v = pp[(size_t)row * 64 + l];
  float gmax = v;
#pragma unroll
  for (int m = 1; m < 64; m <<= 1) gmax = fmaxf(gmax, __shfl_xor(gmax, m));
  bool f = (v >= gmax - MARGIN);
  ull_t b = __ballot(f);
  int cnt = __popcll(b);
  int base = 0;
  if (l == 0) base = atomicAdd(&counters[0], cnt);
  base = __shfl(base, 0);
  if (f) wl[base + __popcll(b & ((1ull << l) - 1ull))] = (row << 6) | l;
}

// -------- exact fp32 rescore of flagged (row, block) pairs: one wave per entry --------
// 16384 waves grid-striding the worklist; packed atomicMax gives min-index tie-break
__global__ __launch_bounds__(256) void rescore(const float* __restrict__ x,
                                               const float* __restrict__ embed,
                                               const float* __restrict__ ehs,
                                               const int* __restrict__ wl,
                                               const int* __restrict__ counters,
                                               ull_t* __restrict__ rowbest) {
  int wid = (blockIdx.x * 256 + threadIdx.x) >> 6;
  int l = threadIdx.x & 63;
  int count = counters[0];
  for (int eidx = wid; eidx < count; eidx += 16384) {
    int entry = wl[eidx];
    int row = entry >> 6;
    int c0 = (entry & 63) * 128;
    const float* xr = x + (size_t)row * D_;
    const float* e0p = embed + (size_t)(c0 + l) * D_;
    const float* e1p = embed + (size_t)(c0 + 64 + l) * D_;
    float a0 = 0.f, a1 = 0.f;
    for (int d = 0; d < D_; d += 4) {
      float4 xv = *(const float4*)(xr + d);
      float4 v0 = *(const float4*)(e0p + d);
      float4 v1 = *(const float4*)(e1p + d);
      a0 = fmaf(v0.x, xv.x, fmaf(v0.y, xv.y, fmaf(v0.z, xv.z, fmaf(v0.w, xv.w, a0))));
      a1 = fmaf(v1.x, xv.x, fmaf(v1.y, xv.y, fmaf(v1.z, xv.z, fmaf(v1.w, xv.w, a1))));
    }
    float s0 = a0 - ehs[c0 + l];
    float s1 = a1 - ehs[c0 + 64 + l];
    float b; int bi;
    if (s1 > s0) { b = s1; bi = c0 + 64 + l; } else { b = s0; bi = c0 + l; }
    unsigned ub = __float_as_uint(b);
    unsigned mb = (ub & 0x80000000u) ? ~ub : (ub | 0x80000000u);
    ull_t packed = ((ull_t)mb << 32) | (0xFFFFFFFFu - (unsigned)bi);
#pragma unroll
    for (int m = 1; m < 64; m <<= 1) {
      ull_t o = __shfl_xor(packed, m);
      if (o > packed) packed = o;
    }
    if (l == 0) atomicMax(&rowbest[row], packed);
  }
}

// -------- write all outputs: gather embed[argmax] + index-as-float --------
__global__ __launch_bounds__(256) void gather(const float* __restrict__ embed,
                                              const ull_t* __restrict__ rowbest,
                                              float* __restrict__ out) {
  int row = (blockIdx.x * 256 + threadIdx.x) >> 6;
  int l = threadIdx.x & 63;
  ull_t p = rowbest[row];
  int idx = (int)(0xFFFFFFFFu - (unsigned)(p & 0xFFFFFFFFu));
  const float4* src = (const float4*)(embed + (size_t)idx * D_);
  float4* dst = (float4*)(out + (size_t)row * D_);
  dst[l] = src[l];
  dst[l + 64] = src[l + 64];
  if (l == 0) out[(size_t)N_ * D_ + row] = (float)idx;
}

extern "C" void kernel_launch(void* const* d_in, const int* in_sizes, int n_in,
                              void* d_out, int out_size, void* d_ws, size_t ws_size,
                              hipStream_t stream) {
  const float* x = (const float*)d_in[0];     // [16384, 512]
  const float* e = (const float*)d_in[1];     // [8192, 512]
  float* out = (float*)d_out;

  char* ws = (char*)d_ws;
  // region A (0..16MB): xb during conv/dist; worklists alias it afterwards
  ushort_t* xb = (ushort_t*)ws;                         // 16 MB
  int* wl = (int*)ws;                                   // 4 MB (max 16384*64 entries)
  int* counters = (int*)(ws + 4194304);                 // 8 B
  ull_t* rowbest = (ull_t*)(ws + 4259840);              // 128 KB
  ushort_t* eb = (ushort_t*)(ws + 16777216);            // 8 MB
  float* ehs = (float*)(ws + 25165824);                 // 32 KB
  float* pp = (float*)(ws + 25198592);                  // 4 MB (N_*64 floats)

  conv_x<<<4096, 256, 0, stream>>>(x, xb);
  conv_e<<<2048, 256, 0, stream>>>(e, eb, ehs);
  dist_mfma<<<dim3(128, 64), 256, 0, stream>>>(xb, eb, ehs, pp);
  init_ws<<<64, 256, 0, stream>>>(counters, rowbest);   // after dist_mfma: aliases xb
  combine<<<4096, 256, 0, stream>>>(pp, wl, counters);
  rescore<<<4096, 256, 0, stream>>>(x, e, ehs, wl, counters, rowbest);
  gather<<<4096, 256, 0, stream>>>(e, rowbest, out);
}

// Round 7
// 472.081 us; speedup vs baseline: 2.4965x; 2.4965x over previous
//
#include <hip/hip_runtime.h>
#include <cstddef>
#include <cstdint>

typedef unsigned short ushort_t;
typedef unsigned long long ull_t;
typedef __attribute__((ext_vector_type(8))) short short8;
typedef __attribute__((ext_vector_type(4))) float f32x4;

constexpr int D_ = 512, K_ = 8192, N_ = 16384;
constexpr float MARGIN = 0.75f;   // >= 2*eps of bf16-MFMA score error (~0.3 bound w.h.p.)

// RNE float->bf16 (data has no NaN)
__device__ __forceinline__ ushort_t f2bf(float f) {
  unsigned u = __float_as_uint(f);
  return (ushort_t)((u + 0x7FFFu + ((u >> 16) & 1u)) >> 16);
}
// order-preserving float->uint flip (max-compatible)
__device__ __forceinline__ unsigned flipf(float s) {
  unsigned u = __float_as_uint(s);
  return (u & 0x80000000u) ? ~u : (u | 0x80000000u);
}
__device__ __forceinline__ float unflipf(unsigned m) {
  unsigned u = (m & 0x80000000u) ? (m ^ 0x80000000u) : ~m;
  return __uint_as_float(u);
}
__device__ __forceinline__ ull_t umax64(ull_t a, ull_t b) { return a > b ? a : b; }
__device__ __forceinline__ ull_t umin64(ull_t a, ull_t b) { return a < b ? a : b; }

__device__ __forceinline__ void gld16(void* l, const void* g) {
  __builtin_amdgcn_global_load_lds((const __attribute__((address_space(1))) void*)g,
                                   (__attribute__((address_space(3))) void*)l, 16, 0, 0);
}

// -------- zero worklist counters + rowbest (runs AFTER dist_mfma; aliases xb_t) --------
__global__ __launch_bounds__(256) void init_ws(int* counters, ull_t* rowbest) {
  int t = blockIdx.x * 256 + threadIdx.x;   // grid 64*256 == N_
  rowbest[t] = 0ull;
  if (t < 2) counters[t] = 0;
}

// -------- convert x -> bf16 in staging-permuted layout --------
// xb_t[tile(128r)][g(16)][kq(4)][r(128)][8 elems] ; chunk linear id == dst order
__global__ __launch_bounds__(256) void conv_x(const float* __restrict__ x, ushort_t* __restrict__ xbt) {
  int t = blockIdx.x * 256 + threadIdx.x;   // 1M chunks
  int r = t & 127, kq = (t >> 7) & 3, g = (t >> 9) & 15, tile = t >> 13;
  int row = tile * 128 + r;
  int d0 = g * 32 + kq * 8;
  const float4* p = (const float4*)(x + (size_t)row * D_ + d0);
  float4 a = p[0], b = p[1];
  short8 v;
  v[0] = (short)f2bf(a.x); v[1] = (short)f2bf(a.y); v[2] = (short)f2bf(a.z); v[3] = (short)f2bf(a.w);
  v[4] = (short)f2bf(b.x); v[5] = (short)f2bf(b.y); v[6] = (short)f2bf(b.z); v[7] = (short)f2bf(b.w);
  *(short8*)(xbt + (size_t)t * 8) = v;
}

// -------- convert embed -> bf16 permuted (64 tiles of 128 cols) --------
__global__ __launch_bounds__(256) void conv_e(const float* __restrict__ e, ushort_t* __restrict__ ebt) {
  int t = blockIdx.x * 256 + threadIdx.x;   // 512K chunks
  int r = t & 127, kq = (t >> 7) & 3, g = (t >> 9) & 15, tile = t >> 13;
  int row = tile * 128 + r;
  int d0 = g * 32 + kq * 8;
  const float4* p = (const float4*)(e + (size_t)row * D_ + d0);
  float4 a = p[0], b = p[1];
  short8 v;
  v[0] = (short)f2bf(a.x); v[1] = (short)f2bf(a.y); v[2] = (short)f2bf(a.z); v[3] = (short)f2bf(a.w);
  v[4] = (short)f2bf(b.x); v[5] = (short)f2bf(b.y); v[6] = (short)f2bf(b.z); v[7] = (short)f2bf(b.w);
  *(short8*)(ebt + (size_t)t * 8) = v;
}

// -------- ehs[k] = 0.5*||e_k||^2 (fp32) --------
__global__ __launch_bounds__(256) void ehs_kernel(const float* __restrict__ embed,
                                                  float* __restrict__ ehs) {
  int w = (blockIdx.x * 256 + threadIdx.x) >> 6;
  int l = threadIdx.x & 63;
  const float4* e4 = (const float4*)(embed + (size_t)w * D_);
  float4 a = e4[l * 2], b = e4[l * 2 + 1];
  float s = a.x * a.x + a.y * a.y + a.z * a.z + a.w * a.w
          + b.x * b.x + b.y * b.y + b.z * b.z + b.w * b.w;
#pragma unroll
  for (int off = 32; off; off >>= 1) s += __shfl_xor(s, off);
  if (l == 0) ehs[w] = 0.5f * s;
}

// -------- MFMA scoring: per (row, 128-col block) packed top-1 (score|invcol) + s2 --------
// grid (N_/128, K_/128), 256 threads (2x2 waves, 64x64 per wave)
__global__ __launch_bounds__(256, 3) void dist_mfma(const ushort_t* __restrict__ xbt,
                                                    const ushort_t* __restrict__ ebt,
                                                    const float* __restrict__ ehs,
                                                    ull_t* __restrict__ ppu,
                                                    float* __restrict__ pps2) {
  __shared__ alignas(16) char lds[16384];
  char* As = lds;            // [kq(4)][row(128)] 16B chunks
  char* Bs = lds + 8192;
  const int tid = threadIdx.x, w = tid >> 6, l = tid & 63;
  const int row0 = blockIdx.x * 128, col0 = blockIdx.y * 128;
  const int wr = w >> 1, wc = w & 1;
  const size_t xtile = (size_t)blockIdx.x * 131072;   // bytes per 128-row tile
  const size_t etile = (size_t)blockIdx.y * 131072;
  const char* xsrc = (const char*)xbt;
  const char* esrc = (const char*)ebt;

  f32x4 acc[4][4] = {};
  for (int g = 0; g < 16; ++g) {
#pragma unroll
    for (int i = 0; i < 2; ++i) {
      gld16(As + w * 2048 + i * 1024, xsrc + xtile + g * 8192 + w * 2048 + i * 1024 + l * 16);
      gld16(Bs + w * 2048 + i * 1024, esrc + etile + g * 8192 + w * 2048 + i * 1024 + l * 16);
    }
    __syncthreads();
    short8 a[4], b[4];
#pragma unroll
    for (int i = 0; i < 4; ++i)
      a[i] = *(const short8*)(As + (l >> 4) * 2048 + (wr * 64 + i * 16 + (l & 15)) * 16);
#pragma unroll
    for (int j = 0; j < 4; ++j)
      b[j] = *(const short8*)(Bs + (l >> 4) * 2048 + (wc * 64 + j * 16 + (l & 15)) * 16);
#pragma unroll
    for (int i = 0; i < 4; ++i)
#pragma unroll
      for (int j = 0; j < 4; ++j)
        acc[i][j] = __builtin_amdgcn_mfma_f32_16x16x32_bf16(a[i], b[j], acc[i][j], 0, 0, 0);
    __syncthreads();
  }

  // ---- epilogue: per-row packed top-1 (u64 max) + second-best score ----
  float eh[4];
  unsigned ic[4];
#pragma unroll
  for (int j = 0; j < 4; ++j) {
    int col = col0 + wc * 64 + j * 16 + (l & 15);
    eh[j] = ehs[col];
    ic[j] = 0xFFFFFFFFu - (unsigned)col;   // larger packed == smaller col on score tie
  }

  const int c = l & 15, g16 = l >> 4;
  ull_t fp = 0; float fs2 = -3e38f;
#pragma unroll
  for (int i = 0; i < 4; ++i) {
    ull_t pv[4]; float s2v[4];
#pragma unroll
    for (int r = 0; r < 4; ++r) {
      float v0 = acc[i][0][r] - eh[0], v1 = acc[i][1][r] - eh[1];
      float v2 = acc[i][2][r] - eh[2], v3 = acc[i][3][r] - eh[3];
      ull_t p0 = ((ull_t)flipf(v0) << 32) | ic[0];
      ull_t p1 = ((ull_t)flipf(v1) << 32) | ic[1];
      ull_t p2 = ((ull_t)flipf(v2) << 32) | ic[2];
      ull_t p3 = ((ull_t)flipf(v3) << 32) | ic[3];
      pv[r] = umax64(umax64(p0, p1), umax64(p2, p3));
      float m01 = fmaxf(v0, v1), n01 = fminf(v0, v1);
      float m23 = fmaxf(v2, v3), n23 = fminf(v2, v3);
      s2v[r] = fmaxf(fminf(m01, m23), fmaxf(n01, n23));   // 2nd of 4
    }
#pragma unroll
    for (int m = 1; m < 16; m <<= 1) {
#pragma unroll
      for (int r = 0; r < 4; ++r) {
        ull_t op = __shfl_xor(pv[r], m);
        float os2 = __shfl_xor(s2v[r], m);
        ull_t lo = umin64(pv[r], op);
        s2v[r] = fmaxf(fmaxf(s2v[r], os2), unflipf((unsigned)(lo >> 32)));
        pv[r] = umax64(pv[r], op);
      }
    }
    if ((c >> 2) == i) {
      int rsel = c & 3;
      fp  = (rsel == 0) ? pv[0]  : (rsel == 1) ? pv[1]  : (rsel == 2) ? pv[2]  : pv[3];
      fs2 = (rsel == 0) ? s2v[0] : (rsel == 1) ? s2v[1] : (rsel == 2) ? s2v[2] : s2v[3];
    }
  }
  const int rib = wr * 64 + (c >> 2) * 16 + g16 * 4 + (c & 3);   // owned row in [0,128)

  // cross-wave (wc) merge via LDS (staging area dead after final __syncthreads)
  ull_t* lp = (ull_t*)lds;              // [2][128]
  float* ls2 = (float*)(lds + 2048);    // [2][128]
  lp[wc * 128 + rib] = fp; ls2[wc * 128 + rib] = fs2;
  __syncthreads();
  if (wc == 0) {
    ull_t op = lp[128 + rib];
    float os2 = ls2[128 + rib];
    ull_t lo = umin64(fp, op);
    fs2 = fmaxf(fmaxf(fs2, os2), unflipf((unsigned)(lo >> 32)));
    fp = umax64(fp, op);
    ppu[(size_t)(row0 + rib) * 64 + blockIdx.y] = fp;
    pps2[(size_t)(row0 + rib) * 64 + blockIdx.y] = fs2;
  }
}

// -------- combine: candidates = block top-1 cols within MARGIN; s2-hit blocks -> full scan --------
__global__ __launch_bounds__(256) void combine(const ull_t* __restrict__ ppu,
                                               const float* __restrict__ pps2,
                                               int* __restrict__ wl, int* __restrict__ wl2,
                                               int* __restrict__ counters) {
  int row = (blockIdx.x * 256 + threadIdx.x) >> 6;
  int l = threadIdx.x & 63;
  ull_t p = ppu[(size_t)row * 64 + l];
  float s2 = pps2[(size_t)row * 64 + l];
  ull_t gp = p;
#pragma unroll
  for (int m = 1; m < 64; m <<= 1) gp = umax64(gp, __shfl_xor(gp, m));
  float gs = unflipf((unsigned)(gp >> 32));
  float t = gs - MARGIN;
  float s1 = unflipf((unsigned)(p >> 32));
  bool cand = (s1 >= t);
  bool ovf = (s2 >= t);
  ull_t b1 = __ballot(cand);
  ull_t b2 = __ballot(ovf);
  int n1 = __popcll(b1), n2 = __popcll(b2);
  int base1 = 0, base2 = 0;
  if (l == 0) {
    base1 = atomicAdd(&counters[0], n1);
    if (n2) base2 = atomicAdd(&counters[1], n2);
  }
  base1 = __shfl(base1, 0); base2 = __shfl(base2, 0);
  ull_t below = (1ull << l) - 1ull;
  if (cand) {
    int col = (int)(0xFFFFFFFFu - (unsigned)(p & 0xFFFFFFFFu));
    wl[base1 + __popcll(b1 & below)] = (row << 13) | col;
  }
  if (ovf) wl2[base2 + __popcll(b2 & below)] = (row << 6) | l;
}

// -------- exact fp32 scoring of single candidate cols: one wave per entry --------
__global__ __launch_bounds__(256) void cand_exact(const float* __restrict__ x,
                                                  const float* __restrict__ embed,
                                                  const float* __restrict__ ehs,
                                                  const int* __restrict__ wl,
                                                  const int* __restrict__ counters,
                                                  ull_t* __restrict__ rowbest) {
  int wid = (blockIdx.x * 256 + threadIdx.x) >> 6;
  int l = threadIdx.x & 63;
  int count = counters[0];
  for (int eidx = wid; eidx < count; eidx += 16384) {
    int entry = wl[eidx];
    int row = entry >> 13, col = entry & 8191;
    float4 xa = *(const float4*)(x + (size_t)row * D_ + l * 8);
    float4 xc = *(const float4*)(x + (size_t)row * D_ + l * 8 + 4);
    float4 ea = *(const float4*)(embed + (size_t)col * D_ + l * 8);
    float4 ec = *(const float4*)(embed + (size_t)col * D_ + l * 8 + 4);
    float s = xa.x * ea.x + xa.y * ea.y + xa.z * ea.z + xa.w * ea.w
            + xc.x * ec.x + xc.y * ec.y + xc.z * ec.z + xc.w * ec.w;
#pragma unroll
    for (int m = 1; m < 64; m <<= 1) s += __shfl_xor(s, m);
    s -= ehs[col];
    if (l == 0) {
      ull_t packed = ((ull_t)flipf(s) << 32) | (0xFFFFFFFFu - (unsigned)col);
      atomicMax(&rowbest[row], packed);
    }
  }
}

// -------- full exact fp32 scan of s2-flagged (row, block): one wave per entry (rare) --------
__global__ __launch_bounds__(256) void fb_full(const float* __restrict__ x,
                                               const float* __restrict__ embed,
                                               const float* __restrict__ ehs,
                                               const int* __restrict__ wl2,
                                               const int* __restrict__ counters,
                                               ull_t* __restrict__ rowbest) {
  int wid = (blockIdx.x * 256 + threadIdx.x) >> 6;
  int l = threadIdx.x & 63;
  int count = counters[1];
  for (int eidx = wid; eidx < count; eidx += 16384) {
    int entry = wl2[eidx];
    int row = entry >> 6;
    int c0 = (entry & 63) * 128;
    const float* xr = x + (size_t)row * D_;
    const float* e0p = embed + (size_t)(c0 + l) * D_;
    const float* e1p = embed + (size_t)(c0 + 64 + l) * D_;
    float a0 = 0.f, a1 = 0.f;
    for (int d = 0; d < D_; d += 4) {
      float4 xv = *(const float4*)(xr + d);
      float4 v0 = *(const float4*)(e0p + d);
      float4 v1 = *(const float4*)(e1p + d);
      a0 = fmaf(v0.x, xv.x, fmaf(v0.y, xv.y, fmaf(v0.z, xv.z, fmaf(v0.w, xv.w, a0))));
      a1 = fmaf(v1.x, xv.x, fmaf(v1.y, xv.y, fmaf(v1.z, xv.z, fmaf(v1.w, xv.w, a1))));
    }
    float s0 = a0 - ehs[c0 + l];
    float s1 = a1 - ehs[c0 + 64 + l];
    ull_t p0 = ((ull_t)flipf(s0) << 32) | (0xFFFFFFFFu - (unsigned)(c0 + l));
    ull_t p1 = ((ull_t)flipf(s1) << 32) | (0xFFFFFFFFu - (unsigned)(c0 + 64 + l));
    ull_t packed = umax64(p0, p1);
#pragma unroll
    for (int m = 1; m < 64; m <<= 1) packed = umax64(packed, __shfl_xor(packed, m));
    if (l == 0) atomicMax(&rowbest[row], packed);
  }
}

// -------- write all outputs: gather embed[argmax] + index-as-float --------
__global__ __launch_bounds__(256) void gather(const float* __restrict__ embed,
                                              const ull_t* __restrict__ rowbest,
                                              float* __restrict__ out) {
  int row = (blockIdx.x * 256 + threadIdx.x) >> 6;
  int l = threadIdx.x & 63;
  ull_t p = rowbest[row];
  int idx = (int)(0xFFFFFFFFu - (unsigned)(p & 0xFFFFFFFFu));
  const float4* src = (const float4*)(embed + (size_t)idx * D_);
  float4* dst = (float4*)(out + (size_t)row * D_);
  dst[l] = src[l];
  dst[l + 64] = src[l + 64];
  if (l == 0) out[(size_t)N_ * D_ + row] = (float)idx;
}

extern "C" void kernel_launch(void* const* d_in, const int* in_sizes, int n_in,
                              void* d_out, int out_size, void* d_ws, size_t ws_size,
                              hipStream_t stream) {
  const float* x = (const float*)d_in[0];     // [16384, 512]
  const float* e = (const float*)d_in[1];     // [8192, 512]
  float* out = (float*)d_out;

  char* ws = (char*)d_ws;
  // region A (0..16MB): xb_t during conv/dist; worklists alias it afterwards
  ushort_t* xbt = (ushort_t*)ws;                        // 16 MB
  int* wl = (int*)ws;                                   // 4 MB (max 1M candidate entries)
  int* wl2 = (int*)(ws + 4194304);                      // 4 MB (max 1M overflow entries)
  int* counters = (int*)(ws + 8388608);                 // 8 B
  ull_t* rowbest = (ull_t*)(ws + 8388672);              // 128 KB
  ushort_t* ebt = (ushort_t*)(ws + 16777216);           // 8 MB
  float* ehs = (float*)(ws + 25165824);                 // 32 KB
  ull_t* ppu = (ull_t*)(ws + 25198592);                 // 8 MB (N_*64 ull)
  float* pps2 = (float*)(ws + 33587200);                // 4 MB (N_*64 float)

  conv_x<<<4096, 256, 0, stream>>>(x, xbt);
  conv_e<<<2048, 256, 0, stream>>>(e, ebt);
  ehs_kernel<<<2048, 256, 0, stream>>>(e, ehs);
  dist_mfma<<<dim3(128, 64), 256, 0, stream>>>(xbt, ebt, ehs, ppu, pps2);
  init_ws<<<64, 256, 0, stream>>>(counters, rowbest);   // after dist_mfma: aliases xb_t
  combine<<<4096, 256, 0, stream>>>(ppu, pps2, wl, wl2, counters);
  cand_exact<<<4096, 256, 0, stream>>>(x, e, ehs, wl, counters, rowbest);
  fb_full<<<4096, 256, 0, stream>>>(x, e, ehs, wl2, counters, rowbest);
  gather<<<4096, 256, 0, stream>>>(e, rowbest, out);
}